// Round 2
// baseline (612.219 us; speedup 1.0000x reference)
//
#include <hip/hip_runtime.h>
#include <hip/hip_bf16.h>
#include <stdint.h>

// BilinearDiscriminator: out = sigmoid((x*mask_x) @ W^T @ (y*mask_y)^T)
// fp32 precision recovered via bf16 hi/lo split (3 MFMA passes: hh + hl + lh).
// R2: XOR-swizzled LDS (kills 8-way bank conflicts), nt output stores
//     (keep inputs L3-resident), 64x64-tile GEMM1 (was 1 block/CU).

typedef __bf16 bf16_t;
typedef bf16_t bf16x8 __attribute__((ext_vector_type(8)));
typedef bf16_t bf16x4 __attribute__((ext_vector_type(4)));
typedef float f32x4 __attribute__((ext_vector_type(4)));

#define N_ROWS 8192
#define M_ROWS 8192
#define DDIM 512
#define BK 32

// async global->LDS, 16B per lane. LDS dest is forced to wave_base + lane*16.
__device__ __forceinline__ void async_cp16(const bf16_t* g, bf16_t* l) {
    __builtin_amdgcn_global_load_lds(
        (const __attribute__((address_space(1))) unsigned int*)(uintptr_t)g,
        (__attribute__((address_space(3))) unsigned int*)(uint32_t)(uintptr_t)l,
        16, 0, 0);
}

// Fused dropout-multiply + fp32 -> (bf16 hi, bf16 lo) split.
__global__ __launch_bounds__(256) void prep_split(
    const float* __restrict__ v, const float* __restrict__ mask,
    bf16_t* __restrict__ hi, bf16_t* __restrict__ lo, int total4) {
    int idx = blockIdx.x * blockDim.x + threadIdx.x;
    if (idx >= total4) return;
    float4 xv = ((const float4*)v)[idx];
    if (mask) {
        float4 mv = ((const float4*)mask)[idx];
        xv.x *= mv.x; xv.y *= mv.y; xv.z *= mv.z; xv.w *= mv.w;
    }
    float vals[4] = {xv.x, xv.y, xv.z, xv.w};
    bf16x4 h, l;
#pragma unroll
    for (int i = 0; i < 4; ++i) {
        bf16_t hh = (bf16_t)vals[i];
        h[i] = hh;
        l[i] = (bf16_t)(vals[i] - (float)hh);
    }
    *(bf16x4*)(hi + (size_t)idx * 4) = h;
    *(bf16x4*)(lo + (size_t)idx * 4) = l;
}

// C[i,j] = sum_k A[i,k]*B[j,k] via Ah*Bh + Ah*Bl + Al*Bh (3 K-segments).
// Tile: BM = MI*32, BN = NI*32 (4 waves in 2x2). TM x TN tile grid (1-D launch).
// LDS layout swizzle: 16B chunk (row r, chunk c) lives at slot r*4 + (c ^ ((r>>1)&3)).
// EPI==0: split fp32 result into Chi/Clo (bf16).  EPI==1: sigmoid -> Cf (fp32, nt).
template <int EPI, int MI, int NI, int TM, int TN>
__global__ __launch_bounds__(256) void gemm_bt(
    const bf16_t* __restrict__ Ahi, const bf16_t* __restrict__ Alo,
    const bf16_t* __restrict__ Bhi, const bf16_t* __restrict__ Blo,
    float* __restrict__ Cf,
    bf16_t* __restrict__ Chi, bf16_t* __restrict__ Clo,
    int ldc) {
    constexpr int BM = MI * 32;
    constexpr int BN = NI * 32;
    constexpr int ASLOT = BM * 4 / 256;  // 16B slots staged per thread (A)
    constexpr int BSLOT = BN * 4 / 256;

    __shared__ __align__(16) bf16_t As[BM * BK];
    __shared__ __align__(16) bf16_t Bs[BN * BK];

    const int tid = threadIdx.x;
    const int lane = tid & 63;
    const int wave = tid >> 6;
    const int wm = (wave & 1) * MI * 16;
    const int wn = (wave >> 1) * NI * 16;

    // supertile swizzle (G=8 rows of tiles per group) for L2/L3 locality
    const int bid = blockIdx.x;
    constexpr int G = 8;
    const int group = bid / (G * TN);
    const int rem = bid - group * (G * TN);
    const int bm = group * G + (rem & (G - 1));
    const int bn = rem / G;

    // MFMA A/B fragment addressing: row/col = lane&15, k-chunk = lane>>4
    const int m0 = lane & 15;
    const int kc = lane >> 4;

    f32x4 acc[MI][NI];
#pragma unroll
    for (int i = 0; i < MI; ++i)
#pragma unroll
        for (int j = 0; j < NI; ++j)
            acc[i][j] = (f32x4){0.f, 0.f, 0.f, 0.f};

    const bf16_t* Aseg[3] = {Ahi, Ahi, Alo};
    const bf16_t* Bseg[3] = {Bhi, Blo, Bhi};

    // swizzle term for fragment reads is mi/ni-invariant (wm, mi*16 are mult of 16)
    const int fsw = kc ^ ((m0 >> 1) & 3);

    for (int seg = 0; seg < 3; ++seg) {
        const bf16_t* Ab = Aseg[seg];
        const bf16_t* Bb = Bseg[seg];
        for (int k0 = 0; k0 < DDIM; k0 += BK) {
            __syncthreads();  // previous iteration's LDS reads done
#pragma unroll
            for (int s = 0; s < ASLOT; ++s) {
                const int slot = tid + s * 256;
                const int r = slot >> 2;
                const int c = (slot & 3) ^ ((r >> 1) & 3);
                async_cp16(Ab + (size_t)(bm * BM + r) * DDIM + k0 + c * 8,
                           &As[slot * 8]);
            }
#pragma unroll
            for (int s = 0; s < BSLOT; ++s) {
                const int slot = tid + s * 256;
                const int r = slot >> 2;
                const int c = (slot & 3) ^ ((r >> 1) & 3);
                async_cp16(Bb + (size_t)(bn * BN + r) * DDIM + k0 + c * 8,
                           &Bs[slot * 8]);
            }
            __syncthreads();  // vmcnt drained at barrier -> LDS data visible

            bf16x8 af[MI], bfr[NI];
#pragma unroll
            for (int mi = 0; mi < MI; ++mi) {
                const int R = wm + mi * 16 + m0;
                af[mi] = *(const bf16x8*)&As[(R * 4 + fsw) * 8];
            }
#pragma unroll
            for (int ni = 0; ni < NI; ++ni) {
                const int R = wn + ni * 16 + m0;
                bfr[ni] = *(const bf16x8*)&Bs[(R * 4 + fsw) * 8];
            }
#pragma unroll
            for (int mi = 0; mi < MI; ++mi)
#pragma unroll
                for (int ni = 0; ni < NI; ++ni)
                    acc[mi][ni] = __builtin_amdgcn_mfma_f32_16x16x32_bf16(
                        af[mi], bfr[ni], acc[mi][ni], 0, 0, 0);
        }
    }

    // epilogue. C/D layout: col = lane&15, row = (lane>>4)*4 + reg  [m89/m91]
    const int ccol = lane & 15;
    const int crow = (lane >> 4) * 4;
#pragma unroll
    for (int mi = 0; mi < MI; ++mi) {
#pragma unroll
        for (int ni = 0; ni < NI; ++ni) {
#pragma unroll
            for (int r = 0; r < 4; ++r) {
                const int i = bm * BM + wm + mi * 16 + crow + r;
                const int j = bn * BN + wn + ni * 16 + ccol;
                const float v = acc[mi][ni][r];
                if (EPI == 1) {
                    const float sv = 1.0f / (1.0f + __expf(-v));
                    __builtin_nontemporal_store(sv, &Cf[(size_t)i * ldc + j]);
                } else {
                    bf16_t h = (bf16_t)v;
                    bf16_t lo = (bf16_t)(v - (float)h);
                    Chi[(size_t)i * ldc + j] = h;
                    Clo[(size_t)i * ldc + j] = lo;
                }
            }
        }
    }
}

extern "C" void kernel_launch(void* const* d_in, const int* in_sizes, int n_in,
                              void* d_out, int out_size, void* d_ws, size_t ws_size,
                              hipStream_t stream) {
    const float* x  = (const float*)d_in[0];
    const float* y  = (const float*)d_in[1];
    const float* mx = (const float*)d_in[2];
    const float* my = (const float*)d_in[3];
    const float* W  = (const float*)d_in[4];
    float* out = (float*)d_out;

    const size_t ND = (size_t)N_ROWS * DDIM;  // 4,194,304
    const size_t WD = (size_t)DDIM * DDIM;    // 262,144

    bf16_t* ws = (bf16_t*)d_ws;
    bf16_t* xd_hi = ws;
    bf16_t* xd_lo = ws + ND;
    bf16_t* yd_hi = ws + 2 * ND;
    bf16_t* yd_lo = ws + 3 * ND;
    bf16_t* xt_hi = ws + 4 * ND;
    bf16_t* xt_lo = ws + 5 * ND;
    bf16_t* W_hi  = ws + 6 * ND;
    bf16_t* W_lo  = ws + 6 * ND + WD;

    // prep: dropout + hi/lo split
    prep_split<<<(int)(ND / 4 / 256), 256, 0, stream>>>(x, mx, xd_hi, xd_lo, (int)(ND / 4));
    prep_split<<<(int)(ND / 4 / 256), 256, 0, stream>>>(y, my, yd_hi, yd_lo, (int)(ND / 4));
    prep_split<<<(int)(WD / 4 / 256), 256, 0, stream>>>(W, nullptr, W_hi, W_lo, (int)(WD / 4));

    // GEMM1: xt[n,k] = sum_d xd[n,d] * W[k,d]  (8192 x 512), 64x64 tiles -> 1024 blocks
    gemm_bt<0, 2, 2, 128, 8><<<128 * 8, 256, 0, stream>>>(
        xd_hi, xd_lo, W_hi, W_lo, nullptr, xt_hi, xt_lo, DDIM);

    // GEMM2: out[n,m] = sigmoid(sum_k xt[n,k] * yd[m,k])  (8192 x 8192), 128x128 tiles
    gemm_bt<1, 4, 4, 64, 64><<<64 * 64, 256, 0, stream>>>(
        xt_hi, xt_lo, yd_hi, yd_lo, out, nullptr, nullptr, M_ROWS);
}

// Round 3
// 508.709 us; speedup vs baseline: 1.2035x; 1.2035x over previous
//
#include <hip/hip_runtime.h>
#include <hip/hip_bf16.h>
#include <stdint.h>

// BilinearDiscriminator: out = sigmoid((x*mask_x) @ W^T @ (y*mask_y)^T)
// fp32 precision via bf16 hi/lo split. R3: FUSED precision segments --
// stage Ah,Al,Bh,Bl per K-step, 48 MFMA per barrier pair (was 16) -> 3x fewer
// barrier drains. XCD-correct supertile order (bn fastest -> per-XCD L2 set
// ~2.3MB). Single fused prep kernel.

typedef __bf16 bf16_t;
typedef bf16_t bf16x8 __attribute__((ext_vector_type(8)));
typedef bf16_t bf16x4 __attribute__((ext_vector_type(4)));
typedef float f32x4 __attribute__((ext_vector_type(4)));

#define N_ROWS 8192
#define M_ROWS 8192
#define DDIM 512
#define BK 32

__device__ __forceinline__ void async_cp16(const bf16_t* g, bf16_t* l) {
    __builtin_amdgcn_global_load_lds(
        (const __attribute__((address_space(1))) unsigned int*)(uintptr_t)g,
        (__attribute__((address_space(3))) unsigned int*)(uint32_t)(uintptr_t)l,
        16, 0, 0);
}

// One kernel for all three dropout+split preps (saves launch gaps).
// blocks [0,4096): x  [4096,8192): y  [8192,8448): W
__global__ __launch_bounds__(256) void prep_all(
    const float* __restrict__ x, const float* __restrict__ mx,
    const float* __restrict__ y, const float* __restrict__ my,
    const float* __restrict__ W,
    bf16_t* __restrict__ xd_hi, bf16_t* __restrict__ xd_lo,
    bf16_t* __restrict__ yd_hi, bf16_t* __restrict__ yd_lo,
    bf16_t* __restrict__ W_hi, bf16_t* __restrict__ W_lo) {
    const int b = blockIdx.x;
    const float* v; const float* m; bf16_t* hi; bf16_t* lo; int idx;
    if (b < 4096)      { v = x; m = mx;      hi = xd_hi; lo = xd_lo; idx = b * 256 + threadIdx.x; }
    else if (b < 8192) { v = y; m = my;      hi = yd_hi; lo = yd_lo; idx = (b - 4096) * 256 + threadIdx.x; }
    else               { v = W; m = nullptr; hi = W_hi;  lo = W_lo;  idx = (b - 8192) * 256 + threadIdx.x; }
    float4 xv = ((const float4*)v)[idx];
    if (m) {
        float4 mv = ((const float4*)m)[idx];
        xv.x *= mv.x; xv.y *= mv.y; xv.z *= mv.z; xv.w *= mv.w;
    }
    float vals[4] = {xv.x, xv.y, xv.z, xv.w};
    bf16x4 h, l;
#pragma unroll
    for (int i = 0; i < 4; ++i) {
        bf16_t hh = (bf16_t)vals[i];
        h[i] = hh;
        l[i] = (bf16_t)(vals[i] - (float)hh);
    }
    *(bf16x4*)(hi + (size_t)idx * 4) = h;
    *(bf16x4*)(lo + (size_t)idx * 4) = l;
}

// C[i,j] = sum_k A[i,k]*B[j,k] via Ah*Bh + Al*Bh + Ah*Bl, fused per K-tile.
// Tile BM=MI*32 x BN=NI*32, 4 waves (2x2). Grid TM x TN tiles, 1-D.
// Supertile order: 8bm x 8bn, bn fastest (-> XCD id), then bm, then
// supertile-col (A panels stay in per-XCD L2), then supertile-row.
// LDS: XOR-swizzled 16B chunks (slot = r*4 + (c ^ ((r>>1)&3))) -> 0 conflicts.
// EPI==0: split fp32 -> Chi/Clo bf16 (cached stores; re-read by GEMM2).
// EPI==1: sigmoid -> Cf fp32 (nontemporal; never re-read).
template <int EPI, int MI, int NI, int TM, int TN>
__global__ __launch_bounds__(256) void gemm_fused(
    const bf16_t* __restrict__ Ahi, const bf16_t* __restrict__ Alo,
    const bf16_t* __restrict__ Bhi, const bf16_t* __restrict__ Blo,
    float* __restrict__ Cf,
    bf16_t* __restrict__ Chi, bf16_t* __restrict__ Clo,
    int ldc) {
    constexpr int BM = MI * 32;
    constexpr int BN = NI * 32;
    constexpr int AS = BM * 4 / 256;  // 16B slots per thread per A tile
    constexpr int BS = BN * 4 / 256;
    constexpr int SN = TN / 8;

    __shared__ __align__(16) bf16_t Ash[BM * BK];
    __shared__ __align__(16) bf16_t Asl[BM * BK];
    __shared__ __align__(16) bf16_t Bsh[BN * BK];
    __shared__ __align__(16) bf16_t Bsl[BN * BK];

    const int tid = threadIdx.x;
    const int lane = tid & 63;
    const int wave = tid >> 6;
    const int wm = (wave & 1) * MI * 16;
    const int wn = (wave >> 1) * NI * 16;

    const int bid = blockIdx.x;
    const int jj = bid & 7;          // bn within supertile (fastest -> XCD)
    const int ii = (bid >> 3) & 7;   // bm within supertile
    const int sc = (bid >> 6) % SN;  // supertile col
    const int sr = (bid >> 6) / SN;  // supertile row
    const int bm = sr * 8 + ii;
    const int bn = sc * 8 + jj;

    const int m0 = lane & 15;
    const int kc = lane >> 4;
    const int fsw = kc ^ ((m0 >> 1) & 3);  // swizzled chunk for fragment reads

    f32x4 acc[MI][NI];
#pragma unroll
    for (int i = 0; i < MI; ++i)
#pragma unroll
        for (int j = 0; j < NI; ++j)
            acc[i][j] = (f32x4){0.f, 0.f, 0.f, 0.f};

    for (int k0 = 0; k0 < DDIM; k0 += BK) {
        __syncthreads();  // previous iteration's LDS reads done
#pragma unroll
        for (int s = 0; s < AS; ++s) {
            const int slot = tid + s * 256;
            const int r = slot >> 2;
            const int c = (slot & 3) ^ ((r >> 1) & 3);
            const size_t g = (size_t)(bm * BM + r) * DDIM + k0 + c * 8;
            async_cp16(Ahi + g, &Ash[slot * 8]);
            async_cp16(Alo + g, &Asl[slot * 8]);
        }
#pragma unroll
        for (int s = 0; s < BS; ++s) {
            const int slot = tid + s * 256;
            const int r = slot >> 2;
            const int c = (slot & 3) ^ ((r >> 1) & 3);
            const size_t g = (size_t)(bn * BN + r) * DDIM + k0 + c * 8;
            async_cp16(Bhi + g, &Bsh[slot * 8]);
            async_cp16(Blo + g, &Bsl[slot * 8]);
        }
        __syncthreads();  // vmcnt drained at barrier -> LDS visible

        bf16x8 ah[MI], bh[NI];
#pragma unroll
        for (int mi = 0; mi < MI; ++mi)
            ah[mi] = *(const bf16x8*)&Ash[((wm + mi * 16 + m0) * 4 + fsw) * 8];
#pragma unroll
        for (int ni = 0; ni < NI; ++ni)
            bh[ni] = *(const bf16x8*)&Bsh[((wn + ni * 16 + m0) * 4 + fsw) * 8];

        // hh
#pragma unroll
        for (int mi = 0; mi < MI; ++mi)
#pragma unroll
            for (int ni = 0; ni < NI; ++ni)
                acc[mi][ni] = __builtin_amdgcn_mfma_f32_16x16x32_bf16(
                    ah[mi], bh[ni], acc[mi][ni], 0, 0, 0);
        // lh (al x bh) -- al scoped to limit register pressure
        {
            bf16x8 al[MI];
#pragma unroll
            for (int mi = 0; mi < MI; ++mi)
                al[mi] = *(const bf16x8*)&Asl[((wm + mi * 16 + m0) * 4 + fsw) * 8];
#pragma unroll
            for (int mi = 0; mi < MI; ++mi)
#pragma unroll
                for (int ni = 0; ni < NI; ++ni)
                    acc[mi][ni] = __builtin_amdgcn_mfma_f32_16x16x32_bf16(
                        al[mi], bh[ni], acc[mi][ni], 0, 0, 0);
        }
        // hl (ah x bl)
        {
            bf16x8 bl[NI];
#pragma unroll
            for (int ni = 0; ni < NI; ++ni)
                bl[ni] = *(const bf16x8*)&Bsl[((wn + ni * 16 + m0) * 4 + fsw) * 8];
#pragma unroll
            for (int mi = 0; mi < MI; ++mi)
#pragma unroll
                for (int ni = 0; ni < NI; ++ni)
                    acc[mi][ni] = __builtin_amdgcn_mfma_f32_16x16x32_bf16(
                        ah[mi], bl[ni], acc[mi][ni], 0, 0, 0);
        }
    }

    // epilogue. C/D layout: col = lane&15, row = (lane>>4)*4 + reg
    const int ccol = lane & 15;
    const int crow = (lane >> 4) * 4;
#pragma unroll
    for (int mi = 0; mi < MI; ++mi) {
#pragma unroll
        for (int ni = 0; ni < NI; ++ni) {
#pragma unroll
            for (int r = 0; r < 4; ++r) {
                const int i = bm * BM + wm + mi * 16 + crow + r;
                const int j = bn * BN + wn + ni * 16 + ccol;
                const float v = acc[mi][ni][r];
                if (EPI == 1) {
                    const float sv = 1.0f / (1.0f + __expf(-v));
                    __builtin_nontemporal_store(sv, &Cf[(size_t)i * ldc + j]);
                } else {
                    bf16_t h = (bf16_t)v;
                    bf16_t lo = (bf16_t)(v - (float)h);
                    Chi[(size_t)i * ldc + j] = h;
                    Clo[(size_t)i * ldc + j] = lo;
                }
            }
        }
    }
}

extern "C" void kernel_launch(void* const* d_in, const int* in_sizes, int n_in,
                              void* d_out, int out_size, void* d_ws, size_t ws_size,
                              hipStream_t stream) {
    const float* x  = (const float*)d_in[0];
    const float* y  = (const float*)d_in[1];
    const float* mx = (const float*)d_in[2];
    const float* my = (const float*)d_in[3];
    const float* W  = (const float*)d_in[4];
    float* out = (float*)d_out;

    const size_t ND = (size_t)N_ROWS * DDIM;  // 4,194,304
    const size_t WD = (size_t)DDIM * DDIM;    // 262,144

    bf16_t* ws = (bf16_t*)d_ws;
    bf16_t* xd_hi = ws;
    bf16_t* xd_lo = ws + ND;
    bf16_t* yd_hi = ws + 2 * ND;
    bf16_t* yd_lo = ws + 3 * ND;
    bf16_t* xt_hi = ws + 4 * ND;
    bf16_t* xt_lo = ws + 5 * ND;
    bf16_t* W_hi  = ws + 6 * ND;
    bf16_t* W_lo  = ws + 6 * ND + WD;

    // fused prep: dropout + hi/lo split for x, y, W in one launch
    prep_all<<<4096 + 4096 + 256, 256, 0, stream>>>(
        x, mx, y, my, W, xd_hi, xd_lo, yd_hi, yd_lo, W_hi, W_lo);

    // GEMM1: xt[n,k] = sum_d xd[n,d]*W[k,d]  (8192x512), 64x64 tiles, 1024 blocks
    gemm_fused<0, 2, 2, 128, 8><<<128 * 8, 256, 0, stream>>>(
        xd_hi, xd_lo, W_hi, W_lo, nullptr, xt_hi, xt_lo, DDIM);

    // GEMM2: out = sigmoid(xt @ yd^T)  (8192x8192), 128x128 tiles, 4096 blocks
    gemm_fused<1, 4, 4, 64, 64><<<64 * 64, 256, 0, stream>>>(
        xt_hi, xt_lo, yd_hi, yd_lo, out, nullptr, nullptr, M_ROWS);
}